// Round 3
// baseline (717.262 us; speedup 1.0000x reference)
//
#include <hip/hip_runtime.h>

// ---------------- problem constants ----------------
#define N_TOK 16384
#define HD    2048
#define BD    128
#define NE    8
#define KEXT  1088   // 1024 (E*B) + 8 bias rows + 56 zero pad (multiple of 64)

typedef float  f32x4  __attribute__((ext_vector_type(4)));
typedef __bf16 bf16x8 __attribute__((ext_vector_type(8)));
typedef unsigned short u16;
typedef unsigned short u16x4 __attribute__((ext_vector_type(4)));

__device__ __forceinline__ u16 f2bf(float f) {
  union { float f; unsigned u; } v; v.f = f;
  unsigned u = v.u;
  return (u16)((u + 0x7FFFu + ((u >> 16) & 1u)) >> 16);
}

__device__ __forceinline__ void gload16(const void* g, void* l) {
  __builtin_amdgcn_global_load_lds(
      (const __attribute__((address_space(1))) void*)g,
      (__attribute__((address_space(3))) void*)l, 16, 0, 0);
}

// ---------------- init: zero aux accumulators ----------------
__global__ void init_aux_k(float* p) {
  if (threadIdx.x < 16) p[threadIdx.x] = 0.f;
}

// ---------------- W1 f32 [E,B,H] -> bf16 [1024,2048] (identity reshape) ----
__global__ __launch_bounds__(256) void conv_w1_k(const float* __restrict__ W1,
                                                 u16* __restrict__ W1b) {
  int i = (blockIdx.x * 256 + threadIdx.x) * 4;
  float4 v = *(const float4*)(W1 + i);
  u16x4 o; o.x = f2bf(v.x); o.y = f2bf(v.y); o.z = f2bf(v.z); o.w = f2bf(v.w);
  *(u16x4*)(W1b + i) = o;
}

// ---------------- W2 [E,H,B] + b2 [E,H] -> Bt2 bf16 [2048][1088] -----------
// Bt2[h][e*128+b] = W2[e,h,b]; Bt2[h][1024+e] = b2[e,h]; rest 0
__global__ __launch_bounds__(256) void conv_w2_k(const float* __restrict__ W2,
                                                 const float* __restrict__ b2,
                                                 u16* __restrict__ Bt2) {
  int i4 = (blockIdx.x * 256 + threadIdx.x) * 4;   // grid sized exactly
  int h = i4 / KEXT, j0 = i4 % KEXT;
  u16x4 o;
  #pragma unroll
  for (int c = 0; c < 4; c++) {
    int j = j0 + c;
    float v;
    if (j < 1024) {
      int e = j >> 7, b = j & 127;
      v = W2[((size_t)e * HD + h) * BD + b];
    } else if (j < 1032) {
      v = b2[(size_t)(j - 1024) * HD + h];
    } else {
      v = 0.f;
    }
    if (c == 0) o.x = f2bf(v); else if (c == 1) o.y = f2bf(v);
    else if (c == 2) o.z = f2bf(v); else o.w = f2bf(v);
  }
  *(u16x4*)(Bt2 + i4) = o;
}

// ---------------- router: logits(fp32) -> softmax -> top2 -> w -------------
// Two-half Wimg LDS cache (32 KiB) so 5 blocks/CU fit; accumulators persist.
__global__ __launch_bounds__(256, 4)
void router_k(const float* __restrict__ x, const float* __restrict__ skin,
              const float* __restrict__ Wimg, const float* __restrict__ Wskin,
              u16* __restrict__ xbf, float* __restrict__ wout,
              u16* __restrict__ h2, float* __restrict__ psum,
              float* __restrict__ cnt) {
  __shared__ float lw[NE * 1024];          // 32 KiB
  __shared__ float red[16];
  int t = threadIdx.x;
  int l = t & 63, wv = t >> 6;
  float acc[4][NE];
  #pragma unroll
  for (int it = 0; it < 4; it++)
    #pragma unroll
    for (int e = 0; e < NE; e++) acc[it][e] = 0.f;

  for (int half = 0; half < 2; half++) {
    __syncthreads();
    // load Wimg[e][half*1024 .. +1024) -> lw[e*1024 ..]
    for (int i = t; i < NE * 256; i += 256) {
      int e = i >> 8, c4 = (i & 255) * 4;
      *(float4*)&lw[e * 1024 + c4] = *(const float4*)&Wimg[(size_t)e * HD + half * 1024 + c4];
    }
    __syncthreads();
    for (int it = 0; it < 4; it++) {
      int n = blockIdx.x * 16 + wv * 4 + it;
      const float* xr = x + (size_t)n * HD + half * 1024;
      u16* xo = xbf + (size_t)n * HD + half * 1024;
      #pragma unroll
      for (int j = 0; j < 4; j++) {
        int base = j * 256 + l * 4;        // lane stride 16B -> conflict-free lw reads
        float4 xv = *(const float4*)&xr[base];
        u16x4 o; o.x = f2bf(xv.x); o.y = f2bf(xv.y); o.z = f2bf(xv.z); o.w = f2bf(xv.w);
        *(u16x4*)&xo[base] = o;
        #pragma unroll
        for (int e = 0; e < NE; e++) {
          const float* wr_ = &lw[e * 1024 + base];
          acc[it][e] += xv.x * wr_[0] + xv.y * wr_[1] + xv.z * wr_[2] + xv.w * wr_[3];
        }
      }
    }
  }

  float pacc = 0.f, cacc = 0.f;
  for (int it = 0; it < 4; it++) {
    int n = blockIdx.x * 16 + wv * 4 + it;
    float logit[NE];
    #pragma unroll
    for (int e = 0; e < NE; e++) {
      float v = acc[it][e];
      for (int off = 32; off >= 1; off >>= 1) v += __shfl_xor(v, off);
      logit[e] = v + skin[n * 3 + 0] * Wskin[e * 3 + 0]
                   + skin[n * 3 + 1] * Wskin[e * 3 + 1]
                   + skin[n * 3 + 2] * Wskin[e * 3 + 2];
    }
    float mx = logit[0];
    #pragma unroll
    for (int e = 1; e < NE; e++) mx = fmaxf(mx, logit[e]);
    float p[NE], s = 0.f;
    #pragma unroll
    for (int e = 0; e < NE; e++) { p[e] = expf(logit[e] - mx); s += p[e]; }
    float inv = 1.f / s;
    #pragma unroll
    for (int e = 0; e < NE; e++) p[e] *= inv;
    // top-2, ties -> lower index (matches jax top_k)
    int i1 = 0; float v1 = p[0];
    #pragma unroll
    for (int e = 1; e < NE; e++) if (p[e] > v1) { v1 = p[e]; i1 = e; }
    int i2 = -1; float v2 = -1.f;
    #pragma unroll
    for (int e = 0; e < NE; e++) if (e != i1 && p[e] > v2) { v2 = p[e]; i2 = e; }
    float denom = v1 + v2 + 1e-6f;
    float w1v = v1 / denom, w2v = v2 / denom;
    float wl = (l == i1) ? w1v : ((l == i2) ? w2v : 0.f);
    if (l < NE) wout[(size_t)n * NE + l] = wl;
    h2[(size_t)n * KEXT + 1024 + l] = (l < NE) ? f2bf(wl) : (u16)0;
    if (l < NE) pacc += p[l];
    if (l == i1 || l == i2) cacc += 1.f;
  }
  // block-level aux reduction
  __syncthreads();
  if (t < 16) red[t] = 0.f;
  __syncthreads();
  if (l < NE) { atomicAdd(&red[l], pacc); atomicAdd(&red[NE + l], cacc); }
  __syncthreads();
  if (t < 8)       atomicAdd(&psum[t], red[t]);
  else if (t < 16) atomicAdd(&cnt[t - 8], red[t]);
}

// ---------------- GEMM C[m,n] = sum_k A[m,k] * Bt[n,k]  (bf16 MFMA) --------
// T2 both-sides swizzle: linear LDS dest (global_load_lds), inverse-swizzled
// global source chunk, XOR-swizzled ds_read address (rule 21 / m201 pattern).
// EPI=1: h2[row][col] = bf16( relu(acc + b1[col]) * w[row*8 + bn] )
// EPI=2: out[row][col] = acc + x[row][col]
template <int EPI>
__global__ __launch_bounds__(256)
void gemm_bt(const u16* __restrict__ A, int lda,
             const u16* __restrict__ Bt, int ldb,
             int K, int NB, int chunk,
             const float* __restrict__ b1, const float* __restrict__ w,
             u16* __restrict__ Hout,
             const float* __restrict__ xres, float* __restrict__ out) {
  __shared__ u16 lA[128 * 64];
  __shared__ u16 lB[128 * 64];
  // XCD-aware swizzle: blocks sharing an A row-panel land on one XCD
  int xcd = blockIdx.x & 7, idxw = blockIdx.x >> 3;
  int lin = xcd * chunk + idxw;
  int bn = lin % NB, bm = lin / NB;

  int t = threadIdx.x;
  int l = t & 63, wv = t >> 6;
  int wr = wv >> 1, wc = wv & 1;
  int r = t >> 3;
  int cl = (t & 7) * 8;                       // linear LDS dest col (elements)
  int cs = (((t & 7) ^ (r & 7))) * 8;         // swizzled global source col

  const u16* Ag = A + (size_t)(bm * 128 + r) * lda + cs;
  const u16* Bg = Bt + (size_t)(bn * 128 + r) * ldb + cs;
  u16* lAp = &lA[r * 64 + cl];
  u16* lBp = &lB[r * 64 + cl];

  int swz = (l & 7) << 4;                     // read-side XOR (rows: R&7 == l&7)

  f32x4 acc[4][4];
  #pragma unroll
  for (int m = 0; m < 4; m++)
    #pragma unroll
    for (int n = 0; n < 4; n++) acc[m][n] = (f32x4){0.f, 0.f, 0.f, 0.f};

  for (int k0 = 0; k0 < K; k0 += 64) {
    #pragma unroll
    for (int i = 0; i < 4; i++) {
      gload16(Ag + (size_t)i * 32 * lda + k0, lAp + i * 32 * 64);
      gload16(Bg + (size_t)i * 32 * ldb + k0, lBp + i * 32 * 64);
    }
    __syncthreads();
    #pragma unroll
    for (int kk = 0; kk < 64; kk += 32) {
      int cb = (kk + (l >> 4) * 8) * 2;       // byte col within row
      int co = cb ^ swz;                      // swizzled byte offset
      bf16x8 a[4], b[4];
      #pragma unroll
      for (int m = 0; m < 4; m++) {
        int Ra = wr * 64 + m * 16 + (l & 15);
        a[m] = *(const bf16x8*)((const char*)lA + Ra * 128 + co);
      }
      #pragma unroll
      for (int n = 0; n < 4; n++) {
        int Rb = wc * 64 + n * 16 + (l & 15);
        b[n] = *(const bf16x8*)((const char*)lB + Rb * 128 + co);
      }
      #pragma unroll
      for (int m = 0; m < 4; m++)
        #pragma unroll
        for (int n = 0; n < 4; n++)
          acc[m][n] = __builtin_amdgcn_mfma_f32_16x16x32_bf16(a[m], b[n], acc[m][n], 0, 0, 0);
    }
    __syncthreads();
  }

  int row0 = bm * 128 + wr * 64 + (l >> 4) * 4;
  int col0 = bn * 128 + wc * 64 + (l & 15);
  if (EPI == 1) {
    #pragma unroll
    for (int n = 0; n < 4; n++) {
      int col = col0 + n * 16;
      float b1v = b1[col];
      #pragma unroll
      for (int m = 0; m < 4; m++) {
        #pragma unroll
        for (int j = 0; j < 4; j++) {
          int row = row0 + m * 16 + j;
          float v = acc[m][n][j] + b1v;
          v = v > 0.f ? v : 0.f;
          v *= w[(size_t)row * NE + bn];
          Hout[(size_t)row * KEXT + col] = f2bf(v);
        }
      }
    }
  } else {
    #pragma unroll
    for (int m = 0; m < 4; m++) {
      #pragma unroll
      for (int j = 0; j < 4; j++) {
        int row = row0 + m * 16 + j;
        const float* xr = xres + (size_t)row * HD;
        float* orow = out + (size_t)row * HD;
        #pragma unroll
        for (int n = 0; n < 4; n++) {
          int col = col0 + n * 16;
          orow[col] = acc[m][n][j] + xr[col];
        }
      }
    }
  }
}

// ---------------- aux loss finalize ----------------
__global__ void aux_fin_k(const float* __restrict__ psum,
                          const float* __restrict__ cnt,
                          float* __restrict__ out) {
  if (threadIdx.x == 0) {
    float a = 0.f;
    for (int e = 0; e < NE; e++)
      a += (psum[e] / (float)N_TOK) * (cnt[e] / (float)N_TOK);
    out[(size_t)N_TOK * HD] = a * (float)NE;
  }
}

// ---------------- launch ----------------
extern "C" void kernel_launch(void* const* d_in, const int* in_sizes, int n_in,
                              void* d_out, int out_size, void* d_ws, size_t ws_size,
                              hipStream_t stream) {
  const float* x     = (const float*)d_in[0];
  const float* skin  = (const float*)d_in[1];
  const float* Wimg  = (const float*)d_in[2];
  const float* Wskin = (const float*)d_in[3];
  const float* W1    = (const float*)d_in[4];
  const float* b1    = (const float*)d_in[5];
  const float* W2    = (const float*)d_in[6];
  const float* b2    = (const float*)d_in[7];
  float* out = (float*)d_out;

  char* ws = (char*)d_ws;
  u16*   xbf  = (u16*)(ws);                                   // 67,108,864 B
  float* wout = (float*)(ws + 67108864);                      //    524,288 B
  u16*   h2   = (u16*)(ws + 67633152);                        // 35,651,584 B
  u16*   W1b  = (u16*)(ws + 103284736);                       //  4,194,304 B
  u16*   Bt2  = (u16*)(ws + 107479040);                       //  4,456,448 B
  float* aux  = (float*)(ws + 111935488);                     // psum[8], cnt[8]
  float* psum = aux;
  float* cnt  = aux + 8;

  init_aux_k<<<1, 64, 0, stream>>>(aux);
  conv_w1_k<<<(NE * BD * HD) / (256 * 4), 256, 0, stream>>>(W1, W1b);
  conv_w2_k<<<(HD * KEXT) / (256 * 4), 256, 0, stream>>>(W2, b2, Bt2);
  router_k<<<N_TOK / 16, 256, 0, stream>>>(x, skin, Wimg, Wskin, xbf, wout, h2,
                                           psum, cnt);
  aux_fin_k<<<1, 64, 0, stream>>>(psum, cnt, out);
  // GEMM1: M=16384, N=1024, K=2048 ; A=xbf, Bt=W1b
  gemm_bt<1><<<(N_TOK / 128) * (1024 / 128), 256, 0, stream>>>(
      xbf, HD, W1b, HD, HD, 1024 / 128, ((N_TOK / 128) * (1024 / 128)) / 8,
      b1, wout, h2, nullptr, nullptr);
  // GEMM2: M=16384, N=2048, K=1088 ; A=h2, Bt=Bt2
  gemm_bt<2><<<(N_TOK / 128) * (HD / 128), 256, 0, stream>>>(
      h2, KEXT, Bt2, KEXT, KEXT, HD / 128, ((N_TOK / 128) * (HD / 128)) / 8,
      nullptr, nullptr, nullptr, x, out);
}

// Round 4
// 516.140 us; speedup vs baseline: 1.3897x; 1.3897x over previous
//
#include <hip/hip_runtime.h>

// ---------------- problem constants ----------------
#define N_TOK 16384
#define HD    2048
#define BD    128
#define NE    8
#define KEXT  1088   // 1024 (E*B) + 8 bias rows + 56 zero pad (multiple of 64)

typedef float  f32x4  __attribute__((ext_vector_type(4)));
typedef __bf16 bf16x8 __attribute__((ext_vector_type(8)));
typedef unsigned short u16;
typedef unsigned short u16x4 __attribute__((ext_vector_type(4)));

__device__ __forceinline__ u16 f2bf(float f) {
  union { float f; unsigned u; } v; v.f = f;
  unsigned u = v.u;
  return (u16)((u + 0x7FFFu + ((u >> 16) & 1u)) >> 16);
}

__device__ __forceinline__ void gload16(const void* g, void* l) {
  __builtin_amdgcn_global_load_lds(
      (const __attribute__((address_space(1))) void*)g,
      (__attribute__((address_space(3))) void*)l, 16, 0, 0);
}

// ---------------- init: zero aux accumulators ----------------
__global__ void init_aux_k(float* p) {
  if (threadIdx.x < 16) p[threadIdx.x] = 0.f;
}

// ---------------- W1 f32 [E,B,H] -> bf16 [1024,2048] (identity reshape) ----
__global__ __launch_bounds__(256) void conv_w1_k(const float* __restrict__ W1,
                                                 u16* __restrict__ W1b) {
  int i = (blockIdx.x * 256 + threadIdx.x) * 4;
  float4 v = *(const float4*)(W1 + i);
  u16x4 o; o.x = f2bf(v.x); o.y = f2bf(v.y); o.z = f2bf(v.z); o.w = f2bf(v.w);
  *(u16x4*)(W1b + i) = o;
}

// ---------------- W2 [E,H,B] + b2 [E,H] -> Bt2 bf16 [2048][1088] -----------
// Bt2[h][e*128+b] = W2[e,h,b]; Bt2[h][1024+e] = b2[e,h]; rest 0
__global__ __launch_bounds__(256) void conv_w2_k(const float* __restrict__ W2,
                                                 const float* __restrict__ b2,
                                                 u16* __restrict__ Bt2) {
  int i4 = (blockIdx.x * 256 + threadIdx.x) * 4;   // grid sized exactly
  int h = i4 / KEXT, j0 = i4 % KEXT;
  u16x4 o;
  #pragma unroll
  for (int c = 0; c < 4; c++) {
    int j = j0 + c;
    float v;
    if (j < 1024) {
      int e = j >> 7, b = j & 127;
      v = W2[((size_t)e * HD + h) * BD + b];
    } else if (j < 1032) {
      v = b2[(size_t)(j - 1024) * HD + h];
    } else {
      v = 0.f;
    }
    if (c == 0) o.x = f2bf(v); else if (c == 1) o.y = f2bf(v);
    else if (c == 2) o.z = f2bf(v); else o.w = f2bf(v);
  }
  *(u16x4*)(Bt2 + i4) = o;
}

// ---------------- router: logits(fp32) -> softmax -> top2 -> w -------------
// Two-half Wimg LDS cache (32 KiB). ALL it-loops unrolled so acc[][] stays
// in VGPRs (rule #20: runtime-indexed arrays go to scratch).
__global__ __launch_bounds__(256)
void router_k(const float* __restrict__ x, const float* __restrict__ skin,
              const float* __restrict__ Wimg, const float* __restrict__ Wskin,
              u16* __restrict__ xbf, float* __restrict__ wout,
              u16* __restrict__ h2, float* __restrict__ psum,
              float* __restrict__ cnt) {
  __shared__ float lw[NE * 1024];          // 32 KiB
  __shared__ float red[16];
  int t = threadIdx.x;
  int l = t & 63, wv = t >> 6;
  float acc[4][NE];
  #pragma unroll
  for (int it = 0; it < 4; it++)
    #pragma unroll
    for (int e = 0; e < NE; e++) acc[it][e] = 0.f;

  for (int half = 0; half < 2; half++) {
    __syncthreads();
    // load Wimg[e][half*1024 .. +1024) -> lw[e*1024 ..]
    for (int i = t; i < NE * 256; i += 256) {
      int e = i >> 8, c4 = (i & 255) * 4;
      *(float4*)&lw[e * 1024 + c4] = *(const float4*)&Wimg[(size_t)e * HD + half * 1024 + c4];
    }
    __syncthreads();
    #pragma unroll
    for (int it = 0; it < 4; it++) {
      int n = blockIdx.x * 16 + wv * 4 + it;
      const float* xr = x + (size_t)n * HD + half * 1024;
      u16* xo = xbf + (size_t)n * HD + half * 1024;
      #pragma unroll
      for (int j = 0; j < 4; j++) {
        int base = j * 256 + l * 4;
        float4 xv = *(const float4*)&xr[base];
        u16x4 o; o.x = f2bf(xv.x); o.y = f2bf(xv.y); o.z = f2bf(xv.z); o.w = f2bf(xv.w);
        *(u16x4*)&xo[base] = o;
        #pragma unroll
        for (int e = 0; e < NE; e++) {
          float4 wv4 = *(const float4*)&lw[e * 1024 + base];   // ds_read_b128, 2-way = free
          acc[it][e] += xv.x * wv4.x + xv.y * wv4.y + xv.z * wv4.z + xv.w * wv4.w;
        }
      }
    }
  }

  float pacc = 0.f, cacc = 0.f;
  #pragma unroll
  for (int it = 0; it < 4; it++) {
    int n = blockIdx.x * 16 + wv * 4 + it;
    float logit[NE];
    #pragma unroll
    for (int e = 0; e < NE; e++) {
      float v = acc[it][e];
      for (int off = 32; off >= 1; off >>= 1) v += __shfl_xor(v, off);
      logit[e] = v + skin[n * 3 + 0] * Wskin[e * 3 + 0]
                   + skin[n * 3 + 1] * Wskin[e * 3 + 1]
                   + skin[n * 3 + 2] * Wskin[e * 3 + 2];
    }
    float mx = logit[0];
    #pragma unroll
    for (int e = 1; e < NE; e++) mx = fmaxf(mx, logit[e]);
    float p[NE], s = 0.f;
    #pragma unroll
    for (int e = 0; e < NE; e++) { p[e] = expf(logit[e] - mx); s += p[e]; }
    float inv = 1.f / s;
    #pragma unroll
    for (int e = 0; e < NE; e++) p[e] *= inv;
    // top-2, ties -> lower index (matches jax top_k)
    int i1 = 0; float v1 = p[0];
    #pragma unroll
    for (int e = 1; e < NE; e++) if (p[e] > v1) { v1 = p[e]; i1 = e; }
    int i2 = -1; float v2 = -1.f;
    #pragma unroll
    for (int e = 0; e < NE; e++) if (e != i1 && p[e] > v2) { v2 = p[e]; i2 = e; }
    float denom = v1 + v2 + 1e-6f;
    float w1v = v1 / denom, w2v = v2 / denom;
    float wl = (l == i1) ? w1v : ((l == i2) ? w2v : 0.f);
    if (l < NE) wout[(size_t)n * NE + l] = wl;
    h2[(size_t)n * KEXT + 1024 + l] = (l < NE) ? f2bf(wl) : (u16)0;
    if (l < NE) pacc += p[l];
    if (l == i1 || l == i2) cacc += 1.f;
  }
  // block-level aux reduction
  __syncthreads();
  if (t < 16) red[t] = 0.f;
  __syncthreads();
  if (l < NE) { atomicAdd(&red[l], pacc); atomicAdd(&red[NE + l], cacc); }
  __syncthreads();
  if (t < 8)       atomicAdd(&psum[t], red[t]);
  else if (t < 16) atomicAdd(&cnt[t - 8], red[t]);
}

// ---------------- GEMM C[m,n] = sum_k A[m,k] * Bt[n,k]  (bf16 MFMA) --------
// T2 both-sides swizzle: linear LDS dest (global_load_lds), inverse-swizzled
// global source chunk, XOR-swizzled ds_read address (rule 21 / m201 pattern).
// EPI=1: h2[row][col] = bf16( relu(acc + b1[col]) * w[row*8 + bn] )
// EPI=2: out[row][col] = acc + x[row][col]
template <int EPI>
__global__ __launch_bounds__(256)
void gemm_bt(const u16* __restrict__ A, int lda,
             const u16* __restrict__ Bt, int ldb,
             int K, int NB, int chunk,
             const float* __restrict__ b1, const float* __restrict__ w,
             u16* __restrict__ Hout,
             const float* __restrict__ xres, float* __restrict__ out) {
  __shared__ u16 lA[128 * 64];
  __shared__ u16 lB[128 * 64];
  // XCD-aware swizzle: blocks sharing an A row-panel land on one XCD
  int xcd = blockIdx.x & 7, idxw = blockIdx.x >> 3;
  int lin = xcd * chunk + idxw;
  int bn = lin % NB, bm = lin / NB;

  int t = threadIdx.x;
  int l = t & 63, wv = t >> 6;
  int wr = wv >> 1, wc = wv & 1;
  int r = t >> 3;
  int cl = (t & 7) * 8;                       // linear LDS dest col (elements)
  int cs = (((t & 7) ^ (r & 7))) * 8;         // swizzled global source col

  const u16* Ag = A + (size_t)(bm * 128 + r) * lda + cs;
  const u16* Bg = Bt + (size_t)(bn * 128 + r) * ldb + cs;
  u16* lAp = &lA[r * 64 + cl];
  u16* lBp = &lB[r * 64 + cl];

  int swz = (l & 7) << 4;                     // read-side XOR (rows: R&7 == l&7)

  f32x4 acc[4][4];
  #pragma unroll
  for (int m = 0; m < 4; m++)
    #pragma unroll
    for (int n = 0; n < 4; n++) acc[m][n] = (f32x4){0.f, 0.f, 0.f, 0.f};

  for (int k0 = 0; k0 < K; k0 += 64) {
    #pragma unroll
    for (int i = 0; i < 4; i++) {
      gload16(Ag + (size_t)i * 32 * lda + k0, lAp + i * 32 * 64);
      gload16(Bg + (size_t)i * 32 * ldb + k0, lBp + i * 32 * 64);
    }
    __syncthreads();
    #pragma unroll
    for (int kk = 0; kk < 64; kk += 32) {
      int cb = (kk + (l >> 4) * 8) * 2;       // byte col within row
      int co = cb ^ swz;                      // swizzled byte offset
      bf16x8 a[4], b[4];
      #pragma unroll
      for (int m = 0; m < 4; m++) {
        int Ra = wr * 64 + m * 16 + (l & 15);
        a[m] = *(const bf16x8*)((const char*)lA + Ra * 128 + co);
      }
      #pragma unroll
      for (int n = 0; n < 4; n++) {
        int Rb = wc * 64 + n * 16 + (l & 15);
        b[n] = *(const bf16x8*)((const char*)lB + Rb * 128 + co);
      }
      #pragma unroll
      for (int m = 0; m < 4; m++)
        #pragma unroll
        for (int n = 0; n < 4; n++)
          acc[m][n] = __builtin_amdgcn_mfma_f32_16x16x32_bf16(a[m], b[n], acc[m][n], 0, 0, 0);
    }
    __syncthreads();
  }

  int row0 = bm * 128 + wr * 64 + (l >> 4) * 4;
  int col0 = bn * 128 + wc * 64 + (l & 15);
  if (EPI == 1) {
    #pragma unroll
    for (int n = 0; n < 4; n++) {
      int col = col0 + n * 16;
      float b1v = b1[col];
      #pragma unroll
      for (int m = 0; m < 4; m++) {
        #pragma unroll
        for (int j = 0; j < 4; j++) {
          int row = row0 + m * 16 + j;
          float v = acc[m][n][j] + b1v;
          v = v > 0.f ? v : 0.f;
          v *= w[(size_t)row * NE + bn];
          Hout[(size_t)row * KEXT + col] = f2bf(v);
        }
      }
    }
  } else {
    #pragma unroll
    for (int m = 0; m < 4; m++) {
      #pragma unroll
      for (int j = 0; j < 4; j++) {
        int row = row0 + m * 16 + j;
        const float* xr = xres + (size_t)row * HD;
        float* orow = out + (size_t)row * HD;
        #pragma unroll
        for (int n = 0; n < 4; n++) {
          int col = col0 + n * 16;
          orow[col] = acc[m][n][j] + xr[col];
        }
      }
    }
  }
}

// ---------------- aux loss finalize ----------------
__global__ void aux_fin_k(const float* __restrict__ psum,
                          const float* __restrict__ cnt,
                          float* __restrict__ out) {
  if (threadIdx.x == 0) {
    float a = 0.f;
    for (int e = 0; e < NE; e++)
      a += (psum[e] / (float)N_TOK) * (cnt[e] / (float)N_TOK);
    out[(size_t)N_TOK * HD] = a * (float)NE;
  }
}

// ---------------- launch ----------------
extern "C" void kernel_launch(void* const* d_in, const int* in_sizes, int n_in,
                              void* d_out, int out_size, void* d_ws, size_t ws_size,
                              hipStream_t stream) {
  const float* x     = (const float*)d_in[0];
  const float* skin  = (const float*)d_in[1];
  const float* Wimg  = (const float*)d_in[2];
  const float* Wskin = (const float*)d_in[3];
  const float* W1    = (const float*)d_in[4];
  const float* b1    = (const float*)d_in[5];
  const float* W2    = (const float*)d_in[6];
  const float* b2    = (const float*)d_in[7];
  float* out = (float*)d_out;

  char* ws = (char*)d_ws;
  u16*   xbf  = (u16*)(ws);                                   // 67,108,864 B
  float* wout = (float*)(ws + 67108864);                      //    524,288 B
  u16*   h2   = (u16*)(ws + 67633152);                        // 35,651,584 B
  u16*   W1b  = (u16*)(ws + 103284736);                       //  4,194,304 B
  u16*   Bt2  = (u16*)(ws + 107479040);                       //  4,456,448 B
  float* aux  = (float*)(ws + 111935488);                     // psum[8], cnt[8]
  float* psum = aux;
  float* cnt  = aux + 8;

  init_aux_k<<<1, 64, 0, stream>>>(aux);
  conv_w1_k<<<(NE * BD * HD) / (256 * 4), 256, 0, stream>>>(W1, W1b);
  conv_w2_k<<<(HD * KEXT) / (256 * 4), 256, 0, stream>>>(W2, b2, Bt2);
  router_k<<<N_TOK / 16, 256, 0, stream>>>(x, skin, Wimg, Wskin, xbf, wout, h2,
                                           psum, cnt);
  aux_fin_k<<<1, 64, 0, stream>>>(psum, cnt, out);
  // GEMM1: M=16384, N=1024, K=2048 ; A=xbf, Bt=W1b
  gemm_bt<1><<<(N_TOK / 128) * (1024 / 128), 256, 0, stream>>>(
      xbf, HD, W1b, HD, HD, 1024 / 128, ((N_TOK / 128) * (1024 / 128)) / 8,
      b1, wout, h2, nullptr, nullptr);
  // GEMM2: M=16384, N=2048, K=1088 ; A=h2, Bt=Bt2
  gemm_bt<2><<<(N_TOK / 128) * (HD / 128), 256, 0, stream>>>(
      h2, KEXT, Bt2, KEXT, KEXT, HD / 128, ((N_TOK / 128) * (HD / 128)) / 8,
      nullptr, nullptr, nullptr, x, out);
}

// Round 6
// 509.952 us; speedup vs baseline: 1.4065x; 1.0121x over previous
//
#include <hip/hip_runtime.h>

// ---------------- problem constants ----------------
#define N_TOK 16384
#define HD    2048
#define BD    128
#define NE    8
#define KEXT  1088   // 1024 (E*B) + 8 bias rows + 56 zero pad (multiple of 64)

typedef float  f32x4  __attribute__((ext_vector_type(4)));
typedef __bf16 bf16x8 __attribute__((ext_vector_type(8)));
typedef unsigned short u16;
typedef unsigned short u16x4 __attribute__((ext_vector_type(4)));

__device__ __forceinline__ u16 f2bf(float f) {
  union { float f; unsigned u; } v; v.f = f;
  unsigned u = v.u;
  return (u16)((u + 0x7FFFu + ((u >> 16) & 1u)) >> 16);
}

__device__ __forceinline__ void gload16(const void* g, void* l) {
  __builtin_amdgcn_global_load_lds(
      (const __attribute__((address_space(1))) void*)g,
      (__attribute__((address_space(3))) void*)l, 16, 0, 0);
}

// ---------------- init: zero aux accumulators ----------------
__global__ void init_aux_k(float* p) {
  if (threadIdx.x < 16) p[threadIdx.x] = 0.f;
}

// ---------------- W1 f32 [E,B,H] -> bf16 [1024,2048] (identity reshape) ----
__global__ __launch_bounds__(256) void conv_w1_k(const float* __restrict__ W1,
                                                 u16* __restrict__ W1b) {
  int i = (blockIdx.x * 256 + threadIdx.x) * 4;
  float4 v = *(const float4*)(W1 + i);
  u16x4 o; o.x = f2bf(v.x); o.y = f2bf(v.y); o.z = f2bf(v.z); o.w = f2bf(v.w);
  *(u16x4*)(W1b + i) = o;
}

// ---------------- W2 [E,H,B] + b2 [E,H] -> Bt2 bf16 [2048][1088] -----------
// Bt2[h][e*128+b] = W2[e,h,b]; Bt2[h][1024+e] = b2[e,h]; rest 0
__global__ __launch_bounds__(256) void conv_w2_k(const float* __restrict__ W2,
                                                 const float* __restrict__ b2,
                                                 u16* __restrict__ Bt2) {
  int i4 = (blockIdx.x * 256 + threadIdx.x) * 4;   // grid sized exactly
  int h = i4 / KEXT, j0 = i4 % KEXT;
  u16x4 o;
  #pragma unroll
  for (int c = 0; c < 4; c++) {
    int j = j0 + c;
    float v;
    if (j < 1024) {
      int e = j >> 7, b = j & 127;
      v = W2[((size_t)e * HD + h) * BD + b];
    } else if (j < 1032) {
      v = b2[(size_t)(j - 1024) * HD + h];
    } else {
      v = 0.f;
    }
    if (c == 0) o.x = f2bf(v); else if (c == 1) o.y = f2bf(v);
    else if (c == 2) o.z = f2bf(v); else o.w = f2bf(v);
  }
  *(u16x4*)(Bt2 + i4) = o;
}

// ---------------- router: logits(fp32) -> softmax -> top2 -> w -------------
// Streaming design: NO Wimg LDS cache (64 KB -> L1/L2-resident by reuse),
// no __syncthreads in the hot path, token-sequential per wave so only
// acc[8] + xv[8] live registers. x row preloaded once, reused for 8 experts.
__global__ __launch_bounds__(256)
void router_k(const float* __restrict__ x, const float* __restrict__ skin,
              const float* __restrict__ Wimg, const float* __restrict__ Wskin,
              u16* __restrict__ xbf, float* __restrict__ wout,
              u16* __restrict__ h2, float* __restrict__ psum,
              float* __restrict__ cnt) {
  __shared__ float red[16];
  int t = threadIdx.x;
  int l = t & 63, wv = t >> 6;
  float pacc = 0.f, cacc = 0.f;    // per-lane expert accumulators (lane<8)

  for (int it = 0; it < 4; it++) {
    int n = blockIdx.x * 16 + wv * 4 + it;
    const float4* xr = (const float4*)(x + (size_t)n * HD);
    u16* xo = xbf + (size_t)n * HD;
    float4 xv[8];
    #pragma unroll
    for (int j = 0; j < 8; j++) {
      xv[j] = xr[j * 64 + l];
      u16x4 o; o.x = f2bf(xv[j].x); o.y = f2bf(xv[j].y);
      o.z = f2bf(xv[j].z); o.w = f2bf(xv[j].w);
      *(u16x4*)(xo + j * 256 + l * 4) = o;
    }
    float acc[NE];
    #pragma unroll
    for (int e = 0; e < NE; e++) {
      const float4* wr = (const float4*)(Wimg + (size_t)e * HD);
      float a = 0.f;
      #pragma unroll
      for (int j = 0; j < 8; j++) {
        float4 w4 = wr[j * 64 + l];
        a += xv[j].x * w4.x + xv[j].y * w4.y + xv[j].z * w4.z + xv[j].w * w4.w;
      }
      acc[e] = a;
    }
    float logit[NE];
    #pragma unroll
    for (int e = 0; e < NE; e++) {
      float v = acc[e];
      for (int off = 32; off >= 1; off >>= 1) v += __shfl_xor(v, off);
      logit[e] = v + skin[n * 3 + 0] * Wskin[e * 3 + 0]
                   + skin[n * 3 + 1] * Wskin[e * 3 + 1]
                   + skin[n * 3 + 2] * Wskin[e * 3 + 2];
    }
    float mx = logit[0];
    #pragma unroll
    for (int e = 1; e < NE; e++) mx = fmaxf(mx, logit[e]);
    float p[NE], s = 0.f;
    #pragma unroll
    for (int e = 0; e < NE; e++) { p[e] = expf(logit[e] - mx); s += p[e]; }
    float inv = 1.f / s;
    #pragma unroll
    for (int e = 0; e < NE; e++) p[e] *= inv;
    // top-2, ties -> lower index (matches jax top_k)
    int i1 = 0; float v1 = p[0];
    #pragma unroll
    for (int e = 1; e < NE; e++) if (p[e] > v1) { v1 = p[e]; i1 = e; }
    int i2 = -1; float v2 = -1.f;
    #pragma unroll
    for (int e = 0; e < NE; e++) if (e != i1 && p[e] > v2) { v2 = p[e]; i2 = e; }
    float denom = v1 + v2 + 1e-6f;
    float w1v = v1 / denom, w2v = v2 / denom;
    float wl = (l == i1) ? w1v : ((l == i2) ? w2v : 0.f);
    if (l < NE) wout[(size_t)n * NE + l] = wl;
    h2[(size_t)n * KEXT + 1024 + l] = (l < NE) ? f2bf(wl) : (u16)0;
    if (l < NE) { pacc += p[l]; cacc += (l == i1 ? 1.f : 0.f) + (l == i2 ? 1.f : 0.f); }
  }
  // block-level aux reduction (tiny LDS, one sync pair)
  __syncthreads();
  if (t < 16) red[t] = 0.f;
  __syncthreads();
  if (l < NE) { atomicAdd(&red[l], pacc); atomicAdd(&red[NE + l], cacc); }
  __syncthreads();
  if (t < 8)       atomicAdd(&psum[t], red[t]);
  else if (t < 16) atomicAdd(&cnt[t - 8], red[t]);
}

// ---------------- GEMM C[m,n] = sum_k A[m,k] * Bt[n,k]  (bf16 MFMA) --------
// T2 both-sides swizzle: linear LDS dest (global_load_lds), inverse-swizzled
// global source chunk, XOR-swizzled ds_read address (rule 21 / m201 pattern).
// EPI=1: h2[row][col] = bf16( relu(acc + b1[col]) * w[row*8 + bn] )
// EPI=2: out[row][col] = acc + x[row][col]
template <int EPI>
__global__ __launch_bounds__(256)
void gemm_bt(const u16* __restrict__ A, int lda,
             const u16* __restrict__ Bt, int ldb,
             int K, int NB, int chunk,
             const float* __restrict__ b1, const float* __restrict__ w,
             u16* __restrict__ Hout,
             const float* __restrict__ xres, float* __restrict__ out) {
  __shared__ u16 lA[128 * 64];
  __shared__ u16 lB[128 * 64];
  // XCD-aware swizzle: blocks sharing an A row-panel land on one XCD
  int xcd = blockIdx.x & 7, idxw = blockIdx.x >> 3;
  int lin = xcd * chunk + idxw;
  int bn = lin % NB, bm = lin / NB;

  int t = threadIdx.x;
  int l = t & 63, wv = t >> 6;
  int wr = wv >> 1, wc = wv & 1;
  int r = t >> 3;
  int cl = (t & 7) * 8;                       // linear LDS dest col (elements)
  int cs = (((t & 7) ^ (r & 7))) * 8;         // swizzled global source col

  const u16* Ag = A + (size_t)(bm * 128 + r) * lda + cs;
  const u16* Bg = Bt + (size_t)(bn * 128 + r) * ldb + cs;
  u16* lAp = &lA[r * 64 + cl];
  u16* lBp = &lB[r * 64 + cl];

  int swz = (l & 7) << 4;                     // read-side XOR (rows: R&7 == l&7)

  f32x4 acc[4][4];
  #pragma unroll
  for (int m = 0; m < 4; m++)
    #pragma unroll
    for (int n = 0; n < 4; n++) acc[m][n] = (f32x4){0.f, 0.f, 0.f, 0.f};

  for (int k0 = 0; k0 < K; k0 += 64) {
    #pragma unroll
    for (int i = 0; i < 4; i++) {
      gload16(Ag + (size_t)i * 32 * lda + k0, lAp + i * 32 * 64);
      gload16(Bg + (size_t)i * 32 * ldb + k0, lBp + i * 32 * 64);
    }
    __syncthreads();
    #pragma unroll
    for (int kk = 0; kk < 64; kk += 32) {
      int cb = (kk + (l >> 4) * 8) * 2;       // byte col within row
      int co = cb ^ swz;                      // swizzled byte offset
      bf16x8 a[4], b[4];
      #pragma unroll
      for (int m = 0; m < 4; m++) {
        int Ra = wr * 64 + m * 16 + (l & 15);
        a[m] = *(const bf16x8*)((const char*)lA + Ra * 128 + co);
      }
      #pragma unroll
      for (int n = 0; n < 4; n++) {
        int Rb = wc * 64 + n * 16 + (l & 15);
        b[n] = *(const bf16x8*)((const char*)lB + Rb * 128 + co);
      }
      #pragma unroll
      for (int m = 0; m < 4; m++)
        #pragma unroll
        for (int n = 0; n < 4; n++)
          acc[m][n] = __builtin_amdgcn_mfma_f32_16x16x32_bf16(a[m], b[n], acc[m][n], 0, 0, 0);
    }
    __syncthreads();
  }

  int row0 = bm * 128 + wr * 64 + (l >> 4) * 4;
  int col0 = bn * 128 + wc * 64 + (l & 15);
  if (EPI == 1) {
    #pragma unroll
    for (int n = 0; n < 4; n++) {
      int col = col0 + n * 16;
      float b1v = b1[col];
      #pragma unroll
      for (int m = 0; m < 4; m++) {
        #pragma unroll
        for (int j = 0; j < 4; j++) {
          int row = row0 + m * 16 + j;
          float v = acc[m][n][j] + b1v;
          v = v > 0.f ? v : 0.f;
          v *= w[(size_t)row * NE + bn];
          Hout[(size_t)row * KEXT + col] = f2bf(v);
        }
      }
    }
  } else {
    #pragma unroll
    for (int m = 0; m < 4; m++) {
      #pragma unroll
      for (int j = 0; j < 4; j++) {
        int row = row0 + m * 16 + j;
        const float* xr = xres + (size_t)row * HD;
        float* orow = out + (size_t)row * HD;
        #pragma unroll
        for (int n = 0; n < 4; n++) {
          int col = col0 + n * 16;
          orow[col] = acc[m][n][j] + xr[col];
        }
      }
    }
  }
}

// ---------------- aux loss finalize ----------------
__global__ void aux_fin_k(const float* __restrict__ psum,
                          const float* __restrict__ cnt,
                          float* __restrict__ out) {
  if (threadIdx.x == 0) {
    float a = 0.f;
    for (int e = 0; e < NE; e++)
      a += (psum[e] / (float)N_TOK) * (cnt[e] / (float)N_TOK);
    out[(size_t)N_TOK * HD] = a * (float)NE;
  }
}

// ---------------- launch ----------------
extern "C" void kernel_launch(void* const* d_in, const int* in_sizes, int n_in,
                              void* d_out, int out_size, void* d_ws, size_t ws_size,
                              hipStream_t stream) {
  const float* x     = (const float*)d_in[0];
  const float* skin  = (const float*)d_in[1];
  const float* Wimg  = (const float*)d_in[2];
  const float* Wskin = (const float*)d_in[3];
  const float* W1    = (const float*)d_in[4];
  const float* b1    = (const float*)d_in[5];
  const float* W2    = (const float*)d_in[6];
  const float* b2    = (const float*)d_in[7];
  float* out = (float*)d_out;

  char* ws = (char*)d_ws;
  u16*   xbf  = (u16*)(ws);                                   // 67,108,864 B
  float* wout = (float*)(ws + 67108864);                      //    524,288 B
  u16*   h2   = (u16*)(ws + 67633152);                        // 35,651,584 B
  u16*   W1b  = (u16*)(ws + 103284736);                       //  4,194,304 B
  u16*   Bt2  = (u16*)(ws + 107479040);                       //  4,456,448 B
  float* aux  = (float*)(ws + 111935488);                     // psum[8], cnt[8]
  float* psum = aux;
  float* cnt  = aux + 8;

  init_aux_k<<<1, 64, 0, stream>>>(aux);
  conv_w1_k<<<(NE * BD * HD) / (256 * 4), 256, 0, stream>>>(W1, W1b);
  conv_w2_k<<<(HD * KEXT) / (256 * 4), 256, 0, stream>>>(W2, b2, Bt2);
  router_k<<<N_TOK / 16, 256, 0, stream>>>(x, skin, Wimg, Wskin, xbf, wout, h2,
                                           psum, cnt);
  aux_fin_k<<<1, 64, 0, stream>>>(psum, cnt, out);
  // GEMM1: M=16384, N=1024, K=2048 ; A=xbf, Bt=W1b
  gemm_bt<1><<<(N_TOK / 128) * (1024 / 128), 256, 0, stream>>>(
      xbf, HD, W1b, HD, HD, 1024 / 128, ((N_TOK / 128) * (1024 / 128)) / 8,
      b1, wout, h2, nullptr, nullptr);
  // GEMM2: M=16384, N=2048, K=1088 ; A=h2, Bt=Bt2
  gemm_bt<2><<<(N_TOK / 128) * (HD / 128), 256, 0, stream>>>(
      h2, KEXT, Bt2, KEXT, KEXT, HD / 128, ((N_TOK / 128) * (HD / 128)) / 8,
      nullptr, nullptr, nullptr, x, out);
}

// Round 8
// 498.605 us; speedup vs baseline: 1.4385x; 1.0228x over previous
//
#include <hip/hip_runtime.h>

// ---------------- problem constants ----------------
#define N_TOK 16384
#define HD    2048
#define BD    128
#define NE    8
#define KEXT  1088   // 1024 (E*B) + 8 bias rows + 56 zero pad (multiple of 64)

typedef float  f32x4  __attribute__((ext_vector_type(4)));
typedef __bf16 bf16x8 __attribute__((ext_vector_type(8)));
typedef unsigned short u16;
typedef unsigned short u16x4 __attribute__((ext_vector_type(4)));

__device__ __forceinline__ u16 f2bf(float f) {
  union { float f; unsigned u; } v; v.f = f;
  unsigned u = v.u;
  return (u16)((u + 0x7FFFu + ((u >> 16) & 1u)) >> 16);
}

__device__ __forceinline__ void gload16(const void* g, void* l) {
  __builtin_amdgcn_global_load_lds(
      (const __attribute__((address_space(1))) void*)g,
      (__attribute__((address_space(3))) void*)l, 16, 0, 0);
}

// ---------------- init: zero aux accumulators ----------------
__global__ void init_aux_k(float* p) {
  if (threadIdx.x < 16) p[threadIdx.x] = 0.f;
}

// ---------------- W1 f32 [E,B,H] -> bf16 [1024,2048] (identity reshape) ----
__global__ __launch_bounds__(256) void conv_w1_k(const float* __restrict__ W1,
                                                 u16* __restrict__ W1b) {
  int i = (blockIdx.x * 256 + threadIdx.x) * 4;
  float4 v = *(const float4*)(W1 + i);
  u16x4 o; o.x = f2bf(v.x); o.y = f2bf(v.y); o.z = f2bf(v.z); o.w = f2bf(v.w);
  *(u16x4*)(W1b + i) = o;
}

// ---------------- W2 [E,H,B] + b2 [E,H] -> Bt2 bf16 [2048][1088] -----------
__global__ __launch_bounds__(256) void conv_w2_k(const float* __restrict__ W2,
                                                 const float* __restrict__ b2,
                                                 u16* __restrict__ Bt2) {
  int i4 = (blockIdx.x * 256 + threadIdx.x) * 4;   // grid sized exactly
  int h = i4 / KEXT, j0 = i4 % KEXT;
  u16x4 o;
  #pragma unroll
  for (int c = 0; c < 4; c++) {
    int j = j0 + c;
    float v;
    if (j < 1024) {
      int e = j >> 7, b = j & 127;
      v = W2[((size_t)e * HD + h) * BD + b];
    } else if (j < 1032) {
      v = b2[(size_t)(j - 1024) * HD + h];
    } else {
      v = 0.f;
    }
    if (c == 0) o.x = f2bf(v); else if (c == 1) o.y = f2bf(v);
    else if (c == 2) o.z = f2bf(v); else o.w = f2bf(v);
  }
  *(u16x4*)(Bt2 + i4) = o;
}

// ---------------- router (unchanged from round 6) --------------------------
__global__ __launch_bounds__(256)
void router_k(const float* __restrict__ x, const float* __restrict__ skin,
              const float* __restrict__ Wimg, const float* __restrict__ Wskin,
              u16* __restrict__ xbf, float* __restrict__ wout,
              u16* __restrict__ h2, float* __restrict__ psum,
              float* __restrict__ cnt) {
  __shared__ float red[16];
  int t = threadIdx.x;
  int l = t & 63, wv = t >> 6;
  float pacc = 0.f, cacc = 0.f;

  for (int it = 0; it < 4; it++) {
    int n = blockIdx.x * 16 + wv * 4 + it;
    const float4* xr = (const float4*)(x + (size_t)n * HD);
    u16* xo = xbf + (size_t)n * HD;
    float4 xv[8];
    #pragma unroll
    for (int j = 0; j < 8; j++) {
      xv[j] = xr[j * 64 + l];
      u16x4 o; o.x = f2bf(xv[j].x); o.y = f2bf(xv[j].y);
      o.z = f2bf(xv[j].z); o.w = f2bf(xv[j].w);
      *(u16x4*)(xo + j * 256 + l * 4) = o;
    }
    float acc[NE];
    #pragma unroll
    for (int e = 0; e < NE; e++) {
      const float4* wr = (const float4*)(Wimg + (size_t)e * HD);
      float a = 0.f;
      #pragma unroll
      for (int j = 0; j < 8; j++) {
        float4 w4 = wr[j * 64 + l];
        a += xv[j].x * w4.x + xv[j].y * w4.y + xv[j].z * w4.z + xv[j].w * w4.w;
      }
      acc[e] = a;
    }
    float logit[NE];
    #pragma unroll
    for (int e = 0; e < NE; e++) {
      float v = acc[e];
      for (int off = 32; off >= 1; off >>= 1) v += __shfl_xor(v, off);
      logit[e] = v + skin[n * 3 + 0] * Wskin[e * 3 + 0]
                   + skin[n * 3 + 1] * Wskin[e * 3 + 1]
                   + skin[n * 3 + 2] * Wskin[e * 3 + 2];
    }
    float mx = logit[0];
    #pragma unroll
    for (int e = 1; e < NE; e++) mx = fmaxf(mx, logit[e]);
    float p[NE], s = 0.f;
    #pragma unroll
    for (int e = 0; e < NE; e++) { p[e] = expf(logit[e] - mx); s += p[e]; }
    float inv = 1.f / s;
    #pragma unroll
    for (int e = 0; e < NE; e++) p[e] *= inv;
    int i1 = 0; float v1 = p[0];
    #pragma unroll
    for (int e = 1; e < NE; e++) if (p[e] > v1) { v1 = p[e]; i1 = e; }
    int i2 = -1; float v2 = -1.f;
    #pragma unroll
    for (int e = 0; e < NE; e++) if (e != i1 && p[e] > v2) { v2 = p[e]; i2 = e; }
    float denom = v1 + v2 + 1e-6f;
    float w1v = v1 / denom, w2v = v2 / denom;
    float wl = (l == i1) ? w1v : ((l == i2) ? w2v : 0.f);
    if (l < NE) wout[(size_t)n * NE + l] = wl;
    h2[(size_t)n * KEXT + 1024 + l] = (l < NE) ? f2bf(wl) : (u16)0;
    if (l < NE) { pacc += p[l]; cacc += (l == i1 ? 1.f : 0.f) + (l == i2 ? 1.f : 0.f); }
  }
  __syncthreads();
  if (t < 16) red[t] = 0.f;
  __syncthreads();
  if (l < NE) { atomicAdd(&red[l], pacc); atomicAdd(&red[NE + l], cacc); }
  __syncthreads();
  if (t < 8)       atomicAdd(&psum[t], red[t]);
  else if (t < 16) atomicAdd(&cnt[t - 8], red[t]);
}

// ---------------- 256x256 8-wave phase-split GEMM (T2+T3+T5) ---------------
// C[m,n] = sum_k A[m,k] * Bt[n,k], bf16 MFMA 16x16x32.
// 512 thr = 8 waves (2M x 4N), per-wave 128x64 out, BK=64, LDS 2x(A+B) 128KB.
// Per K-tile: 4 quadrant-phases {ds_read frags | stage 2 gloads | s_barrier |
// setprio(1) 16 MFMA setprio(0) | s_barrier}; boundary vmcnt(0)+barrier.
// T2 both-sides swizzle: linear LDS dest, inverse-swizzled global src,
// XOR-swizzled ds_read byte addr.
// EPI=1: h2 = bf16(relu(acc+b1[col]) * w[row*8+e]);  EPI=2: out = acc + x.
template <int EPI>
__global__ __launch_bounds__(512, 2)
void gemm256(const u16* __restrict__ A, int lda,
             const u16* __restrict__ Bt, int ldb,
             int K, int NB, int chunk,
             const float* __restrict__ b1, const float* __restrict__ w,
             u16* __restrict__ Hout,
             const float* __restrict__ xres, float* __restrict__ out) {
  __shared__ u16 sm[2][2][256 * 64];       // [buf][A=0/B=1][row][col]

  const int t = threadIdx.x;
  const int l = t & 63, wv = t >> 6;
  const int wm = wv >> 2, wn = wv & 3;
  const int r = t >> 3;                    // staging row 0..63
  const int cdst = (t & 7) * 8;            // linear LDS dest col (elems)
  const int csrc = ((t & 7) ^ (r & 7)) * 8;// inverse-swizzled global col

  int xcd = blockIdx.x & 7, idxw = blockIdx.x >> 3;
  int lin = xcd * chunk + idxw;
  int bn = lin % NB, bm = lin / NB;

  const u16* Ag = A + (size_t)(bm * 256 + r) * lda + csrc;
  const u16* Bg = Bt + (size_t)(bn * 256 + r) * ldb + csrc;

  auto stage = [&](int buf, int i, int k0) {
    gload16(Ag + (size_t)i * 64 * lda + k0, &sm[buf][0][(i * 64 + r) * 64 + cdst]);
    gload16(Bg + (size_t)i * 64 * ldb + k0, &sm[buf][1][(i * 64 + r) * 64 + cdst]);
  };
  auto rdfrag = [&](const u16* base, int row, int kbyte) -> bf16x8 {
    int byte = (row * 128 + kbyte + (l >> 4) * 16) ^ ((row & 7) << 4);
    return *(const bf16x8*)((const char*)base + byte);
  };

  f32x4 acc[8][4];
  #pragma unroll
  for (int m = 0; m < 8; m++)
    #pragma unroll
    for (int n = 0; n < 4; n++) acc[m][n] = (f32x4){0.f, 0.f, 0.f, 0.f};

  bf16x8 afr[4][2];   // current A row-half: 4 m-frags x 2 ksteps
  bf16x8 bfr[4][2];   // full B tile: 4 n-frags x 2 ksteps

  // prologue: stage tile 0 into buf 0, drain, sync
  #pragma unroll
  for (int i = 0; i < 4; i++) stage(0, i, 0);
  asm volatile("s_waitcnt vmcnt(0)" ::: "memory");
  __builtin_amdgcn_s_barrier();
  __builtin_amdgcn_sched_barrier(0);

  int cur = 0;
  for (int k0 = 0; k0 < K; k0 += 64) {
    const u16* cA = sm[cur][0];
    const u16* cB = sm[cur][1];
    const int nxt = cur ^ 1, kn = k0 + 64;
    const bool pf = kn < K;

    // ---- P0: A-half0 (8 rd) + B n0,n1 (4 rd); stage chunk 0; quad(0,0)
    #pragma unroll
    for (int mi = 0; mi < 4; mi++) {
      int row = wm * 128 + mi * 16 + (l & 15);
      afr[mi][0] = rdfrag(cA, row, 0); afr[mi][1] = rdfrag(cA, row, 64);
    }
    #pragma unroll
    for (int n = 0; n < 2; n++) {
      int row = wn * 64 + n * 16 + (l & 15);
      bfr[n][0] = rdfrag(cB, row, 0); bfr[n][1] = rdfrag(cB, row, 64);
    }
    if (pf) stage(nxt, 0, kn);
    __builtin_amdgcn_s_barrier();
    __builtin_amdgcn_s_setprio(1);
    #pragma unroll
    for (int mi = 0; mi < 4; mi++)
      #pragma unroll
      for (int n = 0; n < 2; n++) {
        acc[mi][n] = __builtin_amdgcn_mfma_f32_16x16x32_bf16(afr[mi][0], bfr[n][0], acc[mi][n], 0, 0, 0);
        acc[mi][n] = __builtin_amdgcn_mfma_f32_16x16x32_bf16(afr[mi][1], bfr[n][1], acc[mi][n], 0, 0, 0);
      }
    __builtin_amdgcn_s_setprio(0);
    __builtin_amdgcn_s_barrier();

    // ---- P1: B n2,n3 (4 rd); stage chunk 1; quad(0,1)
    #pragma unroll
    for (int n = 2; n < 4; n++) {
      int row = wn * 64 + n * 16 + (l & 15);
      bfr[n][0] = rdfrag(cB, row, 0); bfr[n][1] = rdfrag(cB, row, 64);
    }
    if (pf) stage(nxt, 1, kn);
    __builtin_amdgcn_s_barrier();
    __builtin_amdgcn_s_setprio(1);
    #pragma unroll
    for (int mi = 0; mi < 4; mi++)
      #pragma unroll
      for (int n = 2; n < 4; n++) {
        acc[mi][n] = __builtin_amdgcn_mfma_f32_16x16x32_bf16(afr[mi][0], bfr[n][0], acc[mi][n], 0, 0, 0);
        acc[mi][n] = __builtin_amdgcn_mfma_f32_16x16x32_bf16(afr[mi][1], bfr[n][1], acc[mi][n], 0, 0, 0);
      }
    __builtin_amdgcn_s_setprio(0);
    __builtin_amdgcn_s_barrier();

    // ---- P2: A-half1 (8 rd); stage chunk 2; quad(1,0)
    #pragma unroll
    for (int mi = 0; mi < 4; mi++) {
      int row = wm * 128 + 64 + mi * 16 + (l & 15);
      afr[mi][0] = rdfrag(cA, row, 0); afr[mi][1] = rdfrag(cA, row, 64);
    }
    if (pf) stage(nxt, 2, kn);
    __builtin_amdgcn_s_barrier();
    __builtin_amdgcn_s_setprio(1);
    #pragma unroll
    for (int mi = 0; mi < 4; mi++)
      #pragma unroll
      for (int n = 0; n < 2; n++) {
        acc[4 + mi][n] = __builtin_amdgcn_mfma_f32_16x16x32_bf16(afr[mi][0], bfr[n][0], acc[4 + mi][n], 0, 0, 0);
        acc[4 + mi][n] = __builtin_amdgcn_mfma_f32_16x16x32_bf16(afr[mi][1], bfr[n][1], acc[4 + mi][n], 0, 0, 0);
      }
    __builtin_amdgcn_s_setprio(0);
    __builtin_amdgcn_s_barrier();

    // ---- P3: stage chunk 3; quad(1,1)
    if (pf) stage(nxt, 3, kn);
    __builtin_amdgcn_s_barrier();
    __builtin_amdgcn_s_setprio(1);
    #pragma unroll
    for (int mi = 0; mi < 4; mi++)
      #pragma unroll
      for (int n = 2; n < 4; n++) {
        acc[4 + mi][n] = __builtin_amdgcn_mfma_f32_16x16x32_bf16(afr[mi][0], bfr[n][0], acc[4 + mi][n], 0, 0, 0);
        acc[4 + mi][n] = __builtin_amdgcn_mfma_f32_16x16x32_bf16(afr[mi][1], bfr[n][1], acc[4 + mi][n], 0, 0, 0);
      }
    __builtin_amdgcn_s_setprio(0);

    // ---- K-tile boundary: drain staged loads, sync, swap
    asm volatile("s_waitcnt vmcnt(0)" ::: "memory");
    __builtin_amdgcn_s_barrier();
    __builtin_amdgcn_sched_barrier(0);
    cur = nxt;
  }

  // ---------------- epilogue ----------------
  if (EPI == 1) {
    int ew = bn * 2 + (wn >> 1);           // expert is wave-constant (BN=256)
    #pragma unroll
    for (int n = 0; n < 4; n++) {
      int col = bn * 256 + wn * 64 + n * 16 + (l & 15);
      float b1v = b1[col];
      #pragma unroll
      for (int m = 0; m < 8; m++) {
        #pragma unroll
        for (int j = 0; j < 4; j++) {
          int row = bm * 256 + wm * 128 + m * 16 + (l >> 4) * 4 + j;
          float v = acc[m][n][j] + b1v;
          v = fmaxf(v, 0.f) * w[(size_t)row * NE + ew];
          Hout[(size_t)row * KEXT + col] = f2bf(v);
        }
      }
    }
  } else {
    #pragma unroll
    for (int m = 0; m < 8; m++) {
      #pragma unroll
      for (int j = 0; j < 4; j++) {
        int row = bm * 256 + wm * 128 + m * 16 + (l >> 4) * 4 + j;
        const float* xr = xres + (size_t)row * HD;
        float* orow = out + (size_t)row * HD;
        #pragma unroll
        for (int n = 0; n < 4; n++) {
          int col = bn * 256 + wn * 64 + n * 16 + (l & 15);
          orow[col] = acc[m][n][j] + xr[col];
        }
      }
    }
  }
}

// ---------------- aux loss finalize ----------------
__global__ void aux_fin_k(const float* __restrict__ psum,
                          const float* __restrict__ cnt,
                          float* __restrict__ out) {
  if (threadIdx.x == 0) {
    float a = 0.f;
    for (int e = 0; e < NE; e++)
      a += (psum[e] / (float)N_TOK) * (cnt[e] / (float)N_TOK);
    out[(size_t)N_TOK * HD] = a * (float)NE;
  }
}

// ---------------- launch ----------------
extern "C" void kernel_launch(void* const* d_in, const int* in_sizes, int n_in,
                              void* d_out, int out_size, void* d_ws, size_t ws_size,
                              hipStream_t stream) {
  const float* x     = (const float*)d_in[0];
  const float* skin  = (const float*)d_in[1];
  const float* Wimg  = (const float*)d_in[2];
  const float* Wskin = (const float*)d_in[3];
  const float* W1    = (const float*)d_in[4];
  const float* b1    = (const float*)d_in[5];
  const float* W2    = (const float*)d_in[6];
  const float* b2    = (const float*)d_in[7];
  float* out = (float*)d_out;

  char* ws = (char*)d_ws;
  u16*   xbf  = (u16*)(ws);                                   // 67,108,864 B
  float* wout = (float*)(ws + 67108864);                      //    524,288 B
  u16*   h2   = (u16*)(ws + 67633152);                        // 35,651,584 B
  u16*   W1b  = (u16*)(ws + 103284736);                       //  4,194,304 B
  u16*   Bt2  = (u16*)(ws + 107479040);                       //  4,456,448 B
  float* aux  = (float*)(ws + 111935488);                     // psum[8], cnt[8]
  float* psum = aux;
  float* cnt  = aux + 8;

  init_aux_k<<<1, 64, 0, stream>>>(aux);
  conv_w1_k<<<(NE * BD * HD) / (256 * 4), 256, 0, stream>>>(W1, W1b);
  conv_w2_k<<<(HD * KEXT) / (256 * 4), 256, 0, stream>>>(W2, b2, Bt2);
  router_k<<<N_TOK / 16, 256, 0, stream>>>(x, skin, Wimg, Wskin, xbf, wout, h2,
                                           psum, cnt);
  aux_fin_k<<<1, 64, 0, stream>>>(psum, cnt, out);
  // GEMM1: M=16384, N=1024, K=2048 ; A=xbf, Bt=W1b ; grid 64x4
  gemm256<1><<<(N_TOK / 256) * (1024 / 256), 512, 0, stream>>>(
      xbf, HD, W1b, HD, HD, 1024 / 256, ((N_TOK / 256) * (1024 / 256)) / 8,
      b1, wout, h2, nullptr, nullptr);
  // GEMM2: M=16384, N=2048, K=1088 ; A=h2, Bt=Bt2 ; grid 64x8
  gemm256<2><<<(N_TOK / 256) * (HD / 256), 512, 0, stream>>>(
      h2, KEXT, Bt2, KEXT, KEXT, HD / 256, ((N_TOK / 256) * (HD / 256)) / 8,
      nullptr, nullptr, nullptr, x, out);
}